// Round 4
// baseline (104255.176 us; speedup 1.0000x reference)
//
#include <hip/hip_runtime.h>
#include <cstddef>

#define TSEQ 256
#define NB   128
#define HID  512
#define G3   1536
#define INDIM 768
#define CH   16
#define NWG  256

typedef unsigned short bfraw;
using short8 = __attribute__((ext_vector_type(8))) short;
using f32x4  = __attribute__((ext_vector_type(4))) float;

__device__ __forceinline__ float bf2f(unsigned int u){ return __uint_as_float(u<<16); }
__device__ __forceinline__ bfraw f2bf(float f){
  unsigned int u = __float_as_uint(f);
  u += 0x7fffu + ((u>>16)&1u);
  return (bfraw)(u>>16);
}
__device__ __forceinline__ float fsig(float x){
  return __builtin_amdgcn_rcpf(1.0f + __expf(-x));
}
__device__ __forceinline__ float ftanh(float x){
  return 1.0f - 2.0f*__builtin_amdgcn_rcpf(1.0f + __expf(2.0f*x));
}

// ---- device-scope grid barrier (monotonic counter, zeroed per launch slot) ----
__device__ __forceinline__ void gbar(unsigned long long* cnt, unsigned long long target){
  __syncthreads();
  if (threadIdx.x == 0){
    __hip_atomic_fetch_add(cnt, 1ull, __ATOMIC_RELEASE, __HIP_MEMORY_SCOPE_AGENT);
    while (__hip_atomic_load(cnt, __ATOMIC_ACQUIRE, __HIP_MEMORY_SCOPE_AGENT) < target)
      __builtin_amdgcn_s_sleep(8);
  }
  __syncthreads();
}

__global__ void init_k(unsigned long long* cnt){
  if (threadIdx.x < 64) cnt[threadIdx.x] = 0ull;
}

// ---- transpose+convert: in fp32 [R][Cc] -> out bf16 [Cc][R] ----
__global__ __launch_bounds__(256)
void tconv_k(const float* __restrict__ in, bfraw* __restrict__ out, int R, int Cc){
  __shared__ float t[32][33];
  int c0 = blockIdx.x*32, r0 = blockIdx.y*32;
  int tx = threadIdx.x&31, ty = threadIdx.x>>5;
  #pragma unroll
  for (int i=0;i<32;i+=8) t[ty+i][tx] = in[(size_t)(r0+ty+i)*Cc + c0+tx];
  __syncthreads();
  #pragma unroll
  for (int i=0;i<32;i+=8) out[(size_t)(c0+ty+i)*R + r0+tx] = f2bf(t[tx][ty+i]);
}

// b_out[g] = bih[g] + sum_e Wih[g,e]*pb[e]
__global__ void fuse_bias_k(const float* __restrict__ Wih, const float* __restrict__ bih,
                            const float* __restrict__ pb, float* __restrict__ bout)
{
  int g = blockIdx.x*256 + threadIdx.x;
  if (g >= G3) return;
  float acc = bih[g];
  const float* w = Wih + (size_t)g*HID;
  for (int e=0;e<HID;e+=4){
    float4 wv = *(const float4*)(w+e);
    float4 pv = *(const float4*)(pb+e);
    acc += wv.x*pv.x + wv.y*pv.y + wv.z*pv.z + wv.w*pv.w;
  }
  bout[g] = acc;
}

// ---- MFMA bf16 GEMM: C[MxN] = A[MxK] * B^T (+bias); z selects operand set ----
template<typename TA, typename TC, bool BIAS>
__global__ __launch_bounds__(256)
void mgemm(const TA* __restrict__ A0, const TA* __restrict__ A1,
           const bfraw* __restrict__ B0, const bfraw* __restrict__ B1,
           const float* __restrict__ bias0, const float* __restrict__ bias1,
           TC* __restrict__ C0, TC* __restrict__ C1,
           int K, int lda, int ldb, int ldc)
{
  const TA* A = blockIdx.z ? A1 : A0;
  const bfraw* B = blockIdx.z ? B1 : B0;
  const float* bias = blockIdx.z ? bias1 : bias0;
  TC* C = blockIdx.z ? C1 : C0;
  __shared__ bfraw Al[128*40];
  __shared__ bfraw Bl[128*40];
  const int tid = threadIdx.x;
  const size_t m0 = (size_t)blockIdx.y*128, n0 = (size_t)blockIdx.x*128;
  const int w = tid>>6, l = tid&63;
  const int wr = (w>>1)*64, wc = (w&1)*64;
  const int fr = l&15, fg = l>>4;
  f32x4 acc[4][4];
  #pragma unroll
  for (int i=0;i<4;++i)
    #pragma unroll
    for (int j=0;j<4;++j) acc[i][j] = (f32x4){0.f,0.f,0.f,0.f};

  const int srow = tid>>1, skc = (tid&1)*16;
  for (int k0=0; k0<K; k0+=32){
    if constexpr (sizeof(TA)==4){
      const float* ap = (const float*)A + (m0+srow)*lda + k0 + skc;
      float4 v0=*(const float4*)ap, v1=*(const float4*)(ap+4),
             v2=*(const float4*)(ap+8), v3=*(const float4*)(ap+12);
      uint4 w0, w1;
      w0.x=(unsigned)f2bf(v0.x)|((unsigned)f2bf(v0.y)<<16);
      w0.y=(unsigned)f2bf(v0.z)|((unsigned)f2bf(v0.w)<<16);
      w0.z=(unsigned)f2bf(v1.x)|((unsigned)f2bf(v1.y)<<16);
      w0.w=(unsigned)f2bf(v1.z)|((unsigned)f2bf(v1.w)<<16);
      w1.x=(unsigned)f2bf(v2.x)|((unsigned)f2bf(v2.y)<<16);
      w1.y=(unsigned)f2bf(v2.z)|((unsigned)f2bf(v2.w)<<16);
      w1.z=(unsigned)f2bf(v3.x)|((unsigned)f2bf(v3.y)<<16);
      w1.w=(unsigned)f2bf(v3.z)|((unsigned)f2bf(v3.w)<<16);
      *(uint4*)&Al[srow*40+skc]   = w0;
      *(uint4*)&Al[srow*40+skc+8] = w1;
    } else {
      const bfraw* ap = (const bfraw*)A + (m0+srow)*lda + k0 + skc;
      *(uint4*)&Al[srow*40+skc]   = *(const uint4*)ap;
      *(uint4*)&Al[srow*40+skc+8] = *(const uint4*)(ap+8);
    }
    {
      const bfraw* bp = B + (n0+srow)*ldb + k0 + skc;
      *(uint4*)&Bl[srow*40+skc]   = *(const uint4*)bp;
      *(uint4*)&Bl[srow*40+skc+8] = *(const uint4*)(bp+8);
    }
    __syncthreads();
    short8 af[4], bfr[4];
    #pragma unroll
    for (int i=0;i<4;++i) af[i]  = *(const short8*)&Al[(wr+i*16+fr)*40 + fg*8];
    #pragma unroll
    for (int j=0;j<4;++j) bfr[j] = *(const short8*)&Bl[(wc+j*16+fr)*40 + fg*8];
    #pragma unroll
    for (int i=0;i<4;++i)
      #pragma unroll
      for (int j=0;j<4;++j)
        acc[i][j] = __builtin_amdgcn_mfma_f32_16x16x32_bf16(af[i], bfr[j], acc[i][j], 0,0,0);
    __syncthreads();
  }
  #pragma unroll
  for (int i=0;i<4;++i){
    #pragma unroll
    for (int j=0;j<4;++j){
      size_t n = n0 + wc + j*16 + fr;
      float bv = BIAS ? bias[n] : 0.f;
      #pragma unroll
      for (int r=0;r<4;++r){
        size_t m = m0 + wr + i*16 + fg*4 + r;
        float v = acc[i][j][r] + bv;
        if constexpr (sizeof(TC)==2) ((bfraw*)C)[m*ldc + n] = f2bf(v);
        else                         ((float*)C)[m*ldc + n] = v;
      }
    }
  }
}

// ---- Phase B: persistent GRU scan over one chunk of CH steps -----------------
// grid 256 = z(2) x btile(8 of 16 b) x ntile(16 of 32 d). block 512 = 16b x 32d.
__global__ __launch_bounds__(512, 2)
void scanB(const float* __restrict__ GIp, const float* __restrict__ GIh,
           const float* __restrict__ Whhp, const float* __restrict__ Whhh,
           const float* __restrict__ bhhp, const float* __restrict__ bhhh,
           float* __restrict__ hst, bfraw* __restrict__ o_p, bfraw* __restrict__ o_h,
           int c0, unsigned long long* __restrict__ cnt)
{
  const int wg = blockIdx.x;
  const int z = wg>>7, rem = wg&127;
  const int b0 = (rem>>4)*16, d0 = (rem&15)*32;
  const float* GI  = z ? GIh : GIp;
  const float* Whh = z ? Whhh : Whhp;
  const float* bhh = z ? bhhh : bhhp;
  bfraw* ob = z ? o_h : o_p;
  float* hz = hst + (size_t)z*2*NB*HID;

  __shared__ float sh[16][HID];   // 32 KB
  const int tid = threadIdx.x;
  const int bl = tid>>5, dl = tid&31;
  const int d = d0+dl, b = b0+bl;

  #pragma clang loop unroll(disable)
  for (int tt=0; tt<CH; ++tt){
    const int t = c0+tt;
    if (t == 0){
      #pragma unroll
      for (int i=0;i<16;++i){
        int l2 = tid + i*512;
        sh[l2>>9][l2&511] = 1.0f;
      }
    } else {
      const float* hp = hz + (size_t)(((t-1)&1))*NB*HID;
      #pragma unroll
      for (int i=0;i<16;++i){
        int l2 = tid + i*512;
        sh[l2>>9][l2&511] = hp[(size_t)(b0 + (l2>>9))*HID + (l2&511)];
      }
    }
    __syncthreads();
    float ar = bhh[d], az = bhh[d+HID], an = bhh[d+2*HID];
    const float* wr = Whh + (size_t)d*HID;
    const float* wz = Whh + (size_t)(d+HID)*HID;
    const float* wn = Whh + (size_t)(d+2*HID)*HID;
    const float* hb = sh[bl];
    for (int k=0;k<HID;k+=4){
      float4 h4 = *(const float4*)(hb+k);
      float4 w0 = *(const float4*)(wr+k);
      float4 w1 = *(const float4*)(wz+k);
      float4 w2 = *(const float4*)(wn+k);
      ar += h4.x*w0.x + h4.y*w0.y + h4.z*w0.z + h4.w*w0.w;
      az += h4.x*w1.x + h4.y*w1.y + h4.z*w1.z + h4.w*w1.w;
      an += h4.x*w2.x + h4.y*w2.y + h4.z*w2.z + h4.w*w2.w;
    }
    const float* gi = GI + ((size_t)tt*NB + b)*G3;
    float r  = fsig(gi[d] + ar);
    float zz = fsig(gi[d+HID] + az);
    float n  = ftanh(gi[d+2*HID] + r*an);
    float hp = sh[bl][d];
    float hv = (1.0f-zz)*n + zz*hp;
    (hz + (size_t)(t&1)*NB*HID)[(size_t)b*HID + d] = hv;
    ob[((size_t)t*NB + b)*HID + d] = f2bf(hv);
    gbar(cnt, (unsigned long long)(tt+1)*NWG);
  }
}

// ---- Phase D: persistent attention-match scan (all 256 steps, 1 launch) -----
// grid 256 WGs x 512 thr.
__global__ __launch_bounds__(512, 2)
void scanD(const bfraw* __restrict__ Whs, const bfraw* __restrict__ o_p,
           const bfraw* __restrict__ o_h,
           const float* __restrict__ W_t, const float* __restrict__ W_m,
           const float* __restrict__ w_e,
           const float* __restrict__ mWih, const float* __restrict__ mWhh,
           const float* __restrict__ mbih, const float* __restrict__ mbhh,
           const float* __restrict__ outW, const float* __restrict__ outb,
           float* __restrict__ hmbuf, float* __restrict__ c_g,
           float* __restrict__ a_g, float* __restrict__ GX1,
           float* __restrict__ out, unsigned long long* __restrict__ cnt)
{
  const int wg = blockIdx.x;
  const int tid = threadIdx.x;
  __shared__ float c_s[HID];
  __shared__ float we_s[HID];
  __shared__ float l_s[TSEQ];
  __shared__ float red[16];
  if (wg < NB) we_s[tid] = w_e[tid];

  unsigned long long base = 0;
  #pragma clang loop unroll(disable)
  for (int t=0; t<TSEQ; ++t){
    const bfraw* xr = o_h + (size_t)t*NB*HID;
    const float* hmR = hmbuf + (size_t)(((t-1)&1)&1)*NB*HID;  // slot (t-1)&1
    float*       hmW = hmbuf + (size_t)(t&1)*NB*HID;

    // ---- stage 1: c[b,e] = x_t @ W_t + h_m @ W_m ----
    {
      const int bt = wg>>4, et = wg&15;
      const int bl = tid>>6, rr = tid&63, el = rr>>1, ks = rr&1;
      const int b = bt*8+bl, e = et*32+el;
      float acc = 0.f;
      if (ks == 0){
        const bfraw* xb = xr + (size_t)b*HID;
        for (int d2=0; d2<HID; ++d2)
          acc = fmaf(bf2f(xb[d2]), W_t[(size_t)d2*HID+e], acc);
      } else if (t == 0){
        for (int d2=0; d2<HID; ++d2) acc += W_m[(size_t)d2*HID+e];
      } else {
        const float* hb = hmR + (size_t)b*HID;
        for (int d2=0; d2<HID; ++d2)
          acc = fmaf(hb[d2], W_m[(size_t)d2*HID+e], acc);
      }
      acc += __shfl_xor(acc, 1);
      if (ks == 0) c_g[(size_t)b*HID+e] = acc;
    }
    gbar(cnt, base + NWG);

    // ---- stage 2: attention (wg<128) || x-part input gates (wg>=128) ----
    if (wg < NB){
      const int b = wg;
      c_s[tid] = c_g[(size_t)b*HID + tid];
      __syncthreads();
      const int wv = tid>>6, lane = tid&63;
      #pragma unroll 2
      for (int i=0;i<32;++i){
        int tq = wv*32 + i;
        const bfraw* row = Whs + ((size_t)tq*NB + b)*HID;
        float s = 0.f;
        #pragma unroll
        for (int j=0;j<8;++j){
          int dd = j*64 + lane;
          s += ftanh(bf2f(row[dd]) + c_s[dd]) * we_s[dd];
        }
        #pragma unroll
        for (int off=32; off; off>>=1) s += __shfl_xor(s, off);
        if (lane==0) l_s[tq] = s;
      }
      __syncthreads();
      float v = -1e30f, e = 0.f;
      if (tid < TSEQ){
        v = l_s[tid];
        float m = v;
        #pragma unroll
        for (int off=32; off; off>>=1) m = fmaxf(m, __shfl_xor(m, off));
        if (lane==0) red[tid>>6] = m;
      }
      __syncthreads();
      float mx = fmaxf(fmaxf(red[0],red[1]), fmaxf(red[2],red[3]));
      if (tid < TSEQ){
        e = __expf(v - mx);
        float s = e;
        #pragma unroll
        for (int off=32; off; off>>=1) s += __shfl_xor(s, off);
        if (lane==0) red[8+(tid>>6)] = s;
      }
      __syncthreads();
      float S = red[8]+red[9]+red[10]+red[11];
      if (tid < TSEQ) l_s[tid] = e * __builtin_amdgcn_rcpf(S);
      __syncthreads();
      float acc = 0.f;
      #pragma unroll 4
      for (int tq=0;tq<TSEQ;++tq)
        acc = fmaf(l_s[tq], bf2f(o_p[((size_t)tq*NB + b)*HID + tid]), acc);
      a_g[(size_t)b*HID + tid] = acc;
    } else {
      const int ns = (wg-NB)*12;
      const int bl = tid>>2, nq = tid&3;
      const int n0 = ns + nq*3;
      const bfraw* xb = xr + (size_t)bl*HID;
      const float* w0 = mWih + (size_t)n0*1024 + HID;
      const float* w1 = w0 + 1024;
      const float* w2 = w1 + 1024;
      float s0 = mbih[n0], s1 = mbih[n0+1], s2 = mbih[n0+2];
      for (int d2=0; d2<HID; d2+=4){
        uint2 u = *(const uint2*)(xb+d2);
        float x0=bf2f(u.x&0xffffu), x1=bf2f(u.x>>16);
        float x2=bf2f(u.y&0xffffu), x3=bf2f(u.y>>16);
        float4 a4=*(const float4*)(w0+d2);
        float4 b4=*(const float4*)(w1+d2);
        float4 c4=*(const float4*)(w2+d2);
        s0 += x0*a4.x + x1*a4.y + x2*a4.z + x3*a4.w;
        s1 += x0*b4.x + x1*b4.y + x2*b4.z + x3*b4.w;
        s2 += x0*c4.x + x1*c4.y + x2*c4.z + x3*c4.w;
      }
      float* g = GX1 + (size_t)bl*G3;
      g[n0] = s0; g[n0+1] = s1; g[n0+2] = s2;
    }
    gbar(cnt, base + 2*NWG);

    // ---- stage 3: a-part gates + h-part gates + state update ----
    {
      const int b = tid>>2, q = tid&3, k0 = q*128;
      const float* av = a_g + (size_t)b*HID;
      const float* hv = hmR + (size_t)b*HID;
      #pragma unroll
      for (int j=0;j<2;++j){
        const int dd = wg*2 + j;
        const float* war = mWih + (size_t)dd*1024;
        const float* waz = mWih + (size_t)(dd+HID)*1024;
        const float* wan = mWih + (size_t)(dd+2*HID)*1024;
        const float* whr = mWhh + (size_t)dd*HID;
        const float* whz = mWhh + (size_t)(dd+HID)*HID;
        const float* whn = mWhh + (size_t)(dd+2*HID)*HID;
        float ar=0,az=0,an=0,hr=0,hz2=0,hn=0;
        if (t == 0){
          for (int k=k0;k<k0+128;k+=4){
            float4 a4=*(const float4*)(av+k);
            float4 r4=*(const float4*)(war+k), z4=*(const float4*)(waz+k), n4=*(const float4*)(wan+k);
            ar += a4.x*r4.x+a4.y*r4.y+a4.z*r4.z+a4.w*r4.w;
            az += a4.x*z4.x+a4.y*z4.y+a4.z*z4.z+a4.w*z4.w;
            an += a4.x*n4.x+a4.y*n4.y+a4.z*n4.z+a4.w*n4.w;
            float4 hr4=*(const float4*)(whr+k), hz4=*(const float4*)(whz+k), hn4=*(const float4*)(whn+k);
            hr += hr4.x+hr4.y+hr4.z+hr4.w;
            hz2 += hz4.x+hz4.y+hz4.z+hz4.w;
            hn += hn4.x+hn4.y+hn4.z+hn4.w;
          }
        } else {
          for (int k=k0;k<k0+128;k+=4){
            float4 a4=*(const float4*)(av+k);
            float4 h4=*(const float4*)(hv+k);
            float4 r4=*(const float4*)(war+k), z4=*(const float4*)(waz+k), n4=*(const float4*)(wan+k);
            ar += a4.x*r4.x+a4.y*r4.y+a4.z*r4.z+a4.w*r4.w;
            az += a4.x*z4.x+a4.y*z4.y+a4.z*z4.z+a4.w*z4.w;
            an += a4.x*n4.x+a4.y*n4.y+a4.z*n4.z+a4.w*n4.w;
            float4 hr4=*(const float4*)(whr+k), hz4=*(const float4*)(whz+k), hn4=*(const float4*)(whn+k);
            hr += h4.x*hr4.x+h4.y*hr4.y+h4.z*hr4.z+h4.w*hr4.w;
            hz2 += h4.x*hz4.x+h4.y*hz4.y+h4.z*hz4.z+h4.w*hz4.w;
            hn += h4.x*hn4.x+h4.y*hn4.y+h4.z*hn4.z+h4.w*hn4.w;
          }
        }
        ar += __shfl_xor(ar,1); ar += __shfl_xor(ar,2);
        az += __shfl_xor(az,1); az += __shfl_xor(az,2);
        an += __shfl_xor(an,1); an += __shfl_xor(an,2);
        hr += __shfl_xor(hr,1); hr += __shfl_xor(hr,2);
        hz2 += __shfl_xor(hz2,1); hz2 += __shfl_xor(hz2,2);
        hn += __shfl_xor(hn,1); hn += __shfl_xor(hn,2);
        if (q == 0){
          const float* g1 = GX1 + (size_t)b*G3;
          float gr = fsig(ar + hr + g1[dd] + mbhh[dd]);
          float gz = fsig(az + hz2 + g1[dd+HID] + mbhh[dd+HID]);
          float gn = ftanh(an + g1[dd+2*HID] + gr*(hn + mbhh[dd+2*HID]));
          float hp = (t==0) ? 1.0f : hv[dd];
          hmW[(size_t)b*HID + dd] = (1.f-gz)*gn + gz*hp;
        }
      }
    }
    gbar(cnt, base + 3*NWG);
    base += 3*NWG;
  }

  // ---- output head: h_star = hm slot ((TSEQ-1)&1) = 1 ----
  if (wg == 0 && tid < NB*3){
    const float* hf = hmbuf + (size_t)((TSEQ-1)&1)*NB*HID;
    int b = tid/3, c = tid%3;
    float acc = outb[c];
    const float* h = hf + (size_t)b*HID;
    const float* w = outW + (size_t)c*HID;
    for (int d2=0; d2<HID; ++d2) acc = fmaf(h[d2], w[d2], acc);
    out[tid] = fmaxf(acc, 0.f);
  }
}

extern "C" void kernel_launch(void* const* d_in, const int* in_sizes, int n_in,
                              void* d_out, int out_size, void* d_ws, size_t ws_size,
                              hipStream_t stream)
{
  const float* Ep    = (const float*)d_in[0];
  const float* Eh    = (const float*)d_in[1];
  const float* p_W   = (const float*)d_in[2];
  const float* p_b   = (const float*)d_in[3];
  const float* h_W   = (const float*)d_in[4];
  const float* h_b   = (const float*)d_in[5];
  const float* pgWih = (const float*)d_in[6];
  const float* pgWhh = (const float*)d_in[7];
  const float* pgbih = (const float*)d_in[8];
  const float* pgbhh = (const float*)d_in[9];
  const float* hgWih = (const float*)d_in[10];
  const float* hgWhh = (const float*)d_in[11];
  const float* hgbih = (const float*)d_in[12];
  const float* hgbhh = (const float*)d_in[13];
  const float* W_s   = (const float*)d_in[14];
  const float* W_t   = (const float*)d_in[15];
  const float* w_e   = (const float*)d_in[16];
  const float* W_m   = (const float*)d_in[17];
  const float* mWih  = (const float*)d_in[18];
  const float* mWhh  = (const float*)d_in[19];
  const float* mbih  = (const float*)d_in[20];
  const float* mbhh  = (const float*)d_in[21];
  const float* outW  = (const float*)d_in[22];
  const float* outb  = (const float*)d_in[23];

  const size_t OB   = (size_t)TSEQ*NB*HID*sizeof(bfraw);   // 33.5 MB
  const size_t RB   = OB;                                  // GI chunks (25.2) / Whs (33.5)
  const size_t WFB  = (size_t)G3*INDIM*sizeof(bfraw);
  const size_t PWTB = (size_t)INDIM*HID*sizeof(bfraw);
  const size_t SQB  = (size_t)HID*HID*sizeof(bfraw);
  const size_t BIASB  = (size_t)G3*sizeof(float);
  const size_t STATEB = (size_t)NB*HID*sizeof(float);      // 256 KB
  const size_t GXB  = (size_t)NB*G3*sizeof(float);         // 768 KB
  const size_t CNTB = 64*sizeof(unsigned long long);
  const size_t needed = 2*OB + RB + 2*WFB + 2*PWTB + SQB + 2*BIASB
                        + 4*STATEB /*hst*/ + 2*STATEB /*hm*/ + 2*STATEB /*c,a*/
                        + GXB + CNTB;
  if (ws_size < needed) return;

  char* p = (char*)d_ws;
  bfraw* o_p_bf = (bfraw*)p; p += OB;
  bfraw* o_h_bf = (bfraw*)p; p += OB;
  char*  Rreg   = p;         p += RB;
  bfraw* Wfp_bf = (bfraw*)p; p += WFB;
  bfraw* Wfh_bf = (bfraw*)p; p += WFB;
  bfraw* pWT_bf = (bfraw*)p; p += PWTB;
  bfraw* hWT_bf = (bfraw*)p; p += PWTB;
  bfraw* WsT_bf = (bfraw*)p; p += SQB;
  float* bfp    = (float*)p; p += BIASB;
  float* bfh    = (float*)p; p += BIASB;
  float* hst    = (float*)p; p += 4*STATEB;   // [2 GRU][2 pingpong][NB][HID]
  float* hmbuf  = (float*)p; p += 2*STATEB;   // [2][NB][HID]
  float* c_g    = (float*)p; p += STATEB;
  float* a_g    = (float*)p; p += STATEB;
  float* GX1    = (float*)p; p += GXB;
  unsigned long long* cnt = (unsigned long long*)p; p += CNTB;

  float* GIp_c = (float*)Rreg;
  float* GIh_c = (float*)(Rreg + (size_t)CH*NB*G3*sizeof(float));
  bfraw* Whs_bf = (bfraw*)Rreg;

  dim3 b256(256), b512(512);

  init_k<<<dim3(1), dim3(64), 0, stream>>>(cnt);

  // ---- Phase A: weight prep (bf16 only where MFMA needs it) ----
  tconv_k<<<dim3(INDIM/32, HID/32), b256, 0, stream>>>(p_W, pWT_bf, HID, INDIM);
  tconv_k<<<dim3(INDIM/32, HID/32), b256, 0, stream>>>(h_W, hWT_bf, HID, INDIM);
  tconv_k<<<dim3(HID/32, HID/32),  b256, 0, stream>>>(W_s, WsT_bf, HID, HID);
  fuse_bias_k<<<dim3(G3/256), b256, 0, stream>>>(pgWih, pgbih, p_b, bfp);
  fuse_bias_k<<<dim3(G3/256), b256, 0, stream>>>(hgWih, hgbih, h_b, bfh);
  // fold: Wf = Wih @ xW  (both branches in one launch via z)
  mgemm<float, bfraw, false><<<dim3(INDIM/128, G3/128, 2), b256, 0, stream>>>(
    pgWih, hgWih, pWT_bf, hWT_bf, nullptr, nullptr, Wfp_bf, Wfh_bf,
    HID, HID, HID, INDIM);

  // ---- Phase B: chunked GI GEMM (z=both branches) + persistent scan ----
  for (int c = 0; c < TSEQ/CH; ++c){
    mgemm<float, float, true><<<dim3(G3/128, (CH*NB)/128, 2), b256, 0, stream>>>(
      Ep + (size_t)c*CH*NB*INDIM, Eh + (size_t)c*CH*NB*INDIM,
      Wfp_bf, Wfh_bf, bfp, bfh, GIp_c, GIh_c,
      INDIM, INDIM, INDIM, G3);
    scanB<<<dim3(NWG), b512, 0, stream>>>(
      GIp_c, GIh_c, pgWhh, hgWhh, pgbhh, hgbhh,
      hst, o_p_bf, o_h_bf, c*CH, cnt + c);
  }

  // ---- Phase C: Whs = o_p @ W_s (overlays GI region) ----
  mgemm<bfraw, bfraw, false><<<dim3(HID/128, (TSEQ*NB)/128, 1), b256, 0, stream>>>(
    o_p_bf, o_p_bf, WsT_bf, WsT_bf, nullptr, nullptr, Whs_bf, Whs_bf,
    HID, HID, HID, HID);

  // ---- Phase D: persistent attention-match scan + fused output head ----
  scanD<<<dim3(NWG), b512, 0, stream>>>(
    Whs_bf, o_p_bf, o_h_bf, W_t, W_m, w_e, mWih, mWhh, mbih, mbhh,
    outW, outb, hmbuf, c_g, a_g, GX1, (float*)d_out, cnt + 16);
}

// Round 5
// 73125.000 us; speedup vs baseline: 1.4257x; 1.4257x over previous
//
#include <hip/hip_runtime.h>
#include <cstddef>

#define TSEQ 256
#define NB   128
#define HID  512
#define G3   1536
#define INDIM 768
#define CH   16
#define NWG  256

typedef unsigned short bfraw;
using short8 = __attribute__((ext_vector_type(8))) short;
using f32x4  = __attribute__((ext_vector_type(4))) float;

__device__ __forceinline__ float bf2f(unsigned int u){ return __uint_as_float(u<<16); }
__device__ __forceinline__ bfraw f2bf(float f){
  unsigned int u = __float_as_uint(f);
  u += 0x7fffu + ((u>>16)&1u);
  return (bfraw)(u>>16);
}
__device__ __forceinline__ float fsig(float x){
  return __builtin_amdgcn_rcpf(1.0f + __expf(-x));
}
__device__ __forceinline__ float ftanh(float x){
  return 1.0f - 2.0f*__builtin_amdgcn_rcpf(1.0f + __expf(2.0f*x));
}

// ---- device-scope grid barrier ----
__device__ __forceinline__ void gbar(unsigned long long* cnt, unsigned long long target){
  __syncthreads();
  if (threadIdx.x == 0){
    __hip_atomic_fetch_add(cnt, 1ull, __ATOMIC_RELEASE, __HIP_MEMORY_SCOPE_AGENT);
    while (__hip_atomic_load(cnt, __ATOMIC_ACQUIRE, __HIP_MEMORY_SCOPE_AGENT) < target)
      __builtin_amdgcn_s_sleep(2);
  }
  __syncthreads();
}

__global__ void init_k(unsigned long long* cnt){
  if (threadIdx.x < 64) cnt[threadIdx.x] = 0ull;
}

// hmbuf = 1.0f ; hm_bf both slots = 1.0bf
__global__ void hminit_k(float* hmbuf, bfraw* hm_bf){
  int i = blockIdx.x*256 + threadIdx.x;   // 65536
  hmbuf[i] = 1.0f;
  hm_bf[i] = (bfraw)0x3f80;
  hm_bf[65536 + i] = (bfraw)0x3f80;
}

// ---- transpose+convert: in fp32 [R][Cc] -> out bf16 [Cc][R] ----
__global__ __launch_bounds__(256)
void tconv_k(const float* __restrict__ in, bfraw* __restrict__ out, int R, int Cc){
  __shared__ float t[32][33];
  int c0 = blockIdx.x*32, r0 = blockIdx.y*32;
  int tx = threadIdx.x&31, ty = threadIdx.x>>5;
  #pragma unroll
  for (int i=0;i<32;i+=8) t[ty+i][tx] = in[(size_t)(r0+ty+i)*Cc + c0+tx];
  __syncthreads();
  #pragma unroll
  for (int i=0;i<32;i+=8) out[(size_t)(c0+ty+i)*R + r0+tx] = f2bf(t[tx][ty+i]);
}

__global__ void cvt_k(const float* __restrict__ in, bfraw* __restrict__ out, int n){
  int i = (blockIdx.x*256 + threadIdx.x)*4;
  if (i >= n) return;
  float4 v = *(const float4*)(in+i);
  uint2 o;
  o.x = (unsigned)f2bf(v.x) | ((unsigned)f2bf(v.y)<<16);
  o.y = (unsigned)f2bf(v.z) | ((unsigned)f2bf(v.w)<<16);
  *(uint2*)(out+i) = o;
}

// W_cat[n'][k], n'=dd*4+g, k<1536. See mapping in comments.
__global__ void wcat_k(const float* __restrict__ mWih, const float* __restrict__ mWhh,
                       bfraw* __restrict__ Wcat){
  // one thread -> 4 consecutive k of one n'
  size_t gid = (size_t)blockIdx.x*256 + threadIdx.x;   // total 2048*1536/4 = 786432
  int np = (int)(gid / 384);        // 1536/4
  int k4 = ((int)(gid % 384))*4;
  int dd = np>>2, g = np&3;
  float v[4];
  #pragma unroll
  for (int j=0;j<4;++j){
    int k = k4+j; float x = 0.f;
    if (g==0)      x = (k<1024) ? mWih[(size_t)dd*1024 + k]        : mWhh[(size_t)dd*512 + (k-1024)];
    else if (g==1) x = (k<1024) ? mWih[(size_t)(512+dd)*1024 + k]  : mWhh[(size_t)(512+dd)*512 + (k-1024)];
    else if (g==2) x = (k<1024) ? mWih[(size_t)(1024+dd)*1024 + k] : 0.f;
    else           x = (k<1024) ? 0.f : mWhh[(size_t)(1024+dd)*512 + (k-1024)];
    v[j] = x;
  }
  uint2 o;
  o.x = (unsigned)f2bf(v[0]) | ((unsigned)f2bf(v[1])<<16);
  o.y = (unsigned)f2bf(v[2]) | ((unsigned)f2bf(v[3])<<16);
  *(uint2*)(Wcat + (size_t)np*1536 + k4) = o;
}

// combined gate biases: bc[0]=bihr+bhhr, bc[1]=bihz+bhhz, bc[2]=bih_n, bc[3]=bhh_n
__global__ void bpack_k(const float* __restrict__ mbih, const float* __restrict__ mbhh,
                        float* __restrict__ bc){
  int dd = blockIdx.x*256 + threadIdx.x;  // 512
  if (dd >= 512) return;
  bc[dd]        = mbih[dd] + mbhh[dd];
  bc[512+dd]    = mbih[512+dd] + mbhh[512+dd];
  bc[1024+dd]   = mbih[1024+dd];
  bc[1536+dd]   = mbhh[1024+dd];
}

// b_out[g] = bih[g] + sum_e Wih[g,e]*pb[e]
__global__ void fuse_bias_k(const float* __restrict__ Wih, const float* __restrict__ bih,
                            const float* __restrict__ pb, float* __restrict__ bout)
{
  int g = blockIdx.x*256 + threadIdx.x;
  if (g >= G3) return;
  float acc = bih[g];
  const float* w = Wih + (size_t)g*HID;
  for (int e=0;e<HID;e+=4){
    float4 wv = *(const float4*)(w+e);
    float4 pv = *(const float4*)(pb+e);
    acc += wv.x*pv.x + wv.y*pv.y + wv.z*pv.z + wv.w*pv.w;
  }
  bout[g] = acc;
}

// ---- MFMA bf16 GEMM: C[MxN] = A[MxK] * B^T (+bias); z selects operand set ----
template<typename TA, typename TC, bool BIAS>
__global__ __launch_bounds__(256)
void mgemm(const TA* __restrict__ A0, const TA* __restrict__ A1,
           const bfraw* __restrict__ B0, const bfraw* __restrict__ B1,
           const float* __restrict__ bias0, const float* __restrict__ bias1,
           TC* __restrict__ C0, TC* __restrict__ C1,
           int K, int lda, int ldb, int ldc)
{
  const TA* A = blockIdx.z ? A1 : A0;
  const bfraw* B = blockIdx.z ? B1 : B0;
  const float* bias = blockIdx.z ? bias1 : bias0;
  TC* C = blockIdx.z ? C1 : C0;
  __shared__ bfraw Al[128*40];
  __shared__ bfraw Bl[128*40];
  const int tid = threadIdx.x;
  const size_t m0 = (size_t)blockIdx.y*128, n0 = (size_t)blockIdx.x*128;
  const int w = tid>>6, l = tid&63;
  const int wr = (w>>1)*64, wc = (w&1)*64;
  const int fr = l&15, fg = l>>4;
  f32x4 acc[4][4];
  #pragma unroll
  for (int i=0;i<4;++i)
    #pragma unroll
    for (int j=0;j<4;++j) acc[i][j] = (f32x4){0.f,0.f,0.f,0.f};

  const int srow = tid>>1, skc = (tid&1)*16;
  for (int k0=0; k0<K; k0+=32){
    if constexpr (sizeof(TA)==4){
      const float* ap = (const float*)A + (m0+srow)*lda + k0 + skc;
      float4 v0=*(const float4*)ap, v1=*(const float4*)(ap+4),
             v2=*(const float4*)(ap+8), v3=*(const float4*)(ap+12);
      uint4 w0, w1;
      w0.x=(unsigned)f2bf(v0.x)|((unsigned)f2bf(v0.y)<<16);
      w0.y=(unsigned)f2bf(v0.z)|((unsigned)f2bf(v0.w)<<16);
      w0.z=(unsigned)f2bf(v1.x)|((unsigned)f2bf(v1.y)<<16);
      w0.w=(unsigned)f2bf(v1.z)|((unsigned)f2bf(v1.w)<<16);
      w1.x=(unsigned)f2bf(v2.x)|((unsigned)f2bf(v2.y)<<16);
      w1.y=(unsigned)f2bf(v2.z)|((unsigned)f2bf(v2.w)<<16);
      w1.z=(unsigned)f2bf(v3.x)|((unsigned)f2bf(v3.y)<<16);
      w1.w=(unsigned)f2bf(v3.z)|((unsigned)f2bf(v3.w)<<16);
      *(uint4*)&Al[srow*40+skc]   = w0;
      *(uint4*)&Al[srow*40+skc+8] = w1;
    } else {
      const bfraw* ap = (const bfraw*)A + (m0+srow)*lda + k0 + skc;
      *(uint4*)&Al[srow*40+skc]   = *(const uint4*)ap;
      *(uint4*)&Al[srow*40+skc+8] = *(const uint4*)(ap+8);
    }
    {
      const bfraw* bp = B + (n0+srow)*ldb + k0 + skc;
      *(uint4*)&Bl[srow*40+skc]   = *(const uint4*)bp;
      *(uint4*)&Bl[srow*40+skc+8] = *(const uint4*)(bp+8);
    }
    __syncthreads();
    short8 af[4], bfr[4];
    #pragma unroll
    for (int i=0;i<4;++i) af[i]  = *(const short8*)&Al[(wr+i*16+fr)*40 + fg*8];
    #pragma unroll
    for (int j=0;j<4;++j) bfr[j] = *(const short8*)&Bl[(wc+j*16+fr)*40 + fg*8];
    #pragma unroll
    for (int i=0;i<4;++i)
      #pragma unroll
      for (int j=0;j<4;++j)
        acc[i][j] = __builtin_amdgcn_mfma_f32_16x16x32_bf16(af[i], bfr[j], acc[i][j], 0,0,0);
    __syncthreads();
  }
  #pragma unroll
  for (int i=0;i<4;++i){
    #pragma unroll
    for (int j=0;j<4;++j){
      size_t n = n0 + wc + j*16 + fr;
      float bv = BIAS ? bias[n] : 0.f;
      #pragma unroll
      for (int r=0;r<4;++r){
        size_t m = m0 + wr + i*16 + fg*4 + r;
        float v = acc[i][j][r] + bv;
        if constexpr (sizeof(TC)==2) ((bfraw*)C)[m*ldc + n] = f2bf(v);
        else                         ((float*)C)[m*ldc + n] = v;
      }
    }
  }
}

// ---- Phase B: persistent GRU scan, weights LDS-resident, dyn LDS 131072 ----
// 256 WGs = z(2) x bg(8 of 16 b) x dg(16 of 32 d); 512 thr = 16b x 32d
__global__ __launch_bounds__(512, 2)
void scanB(const float* __restrict__ GIp, const float* __restrict__ GIh,
           const bfraw* __restrict__ Whhp, const bfraw* __restrict__ Whhh,
           const float* __restrict__ bhhp, const float* __restrict__ bhhh,
           float* __restrict__ hst, bfraw* __restrict__ o_p, bfraw* __restrict__ o_h,
           int c0, unsigned long long* __restrict__ cnt)
{
  extern __shared__ char smem[];
  bfraw* wl = (bfraw*)smem;                  // [3][128][32][4] = 49152 bfraw = 98304 B
  float* sh = (float*)(smem + 98304);        // [16][512] = 32768 B
  const int wg = blockIdx.x;
  const int z = wg>>7, rem = wg&127;
  const int bg = rem>>4, dg = rem&15;
  const float* GI  = z ? GIh : GIp;
  const bfraw* Wb  = z ? Whhh : Whhp;
  const float* bhh = z ? bhhh : bhhp;
  bfraw* ob = z ? o_h : o_p;
  float* hz = hst + (size_t)z*2*NB*HID;
  const int tid = threadIdx.x;

  // preload weights: rows g*512 + dg*32 .. +32  (each row 512 bf16)
  #pragma unroll
  for (int g=0; g<3; ++g){
    const unsigned* src = (const unsigned*)(Wb + (size_t)(g*512 + dg*32)*512);
    for (int j=0; j<16; ++j){
      int iu = tid + j*512;          // 8192 uints
      unsigned v = src[iu];
      int d = iu>>8, kk = (iu&255)*2;
      int idx0 = g*16384 + (kk>>2)*128 + d*4 + (kk&3);
      *((unsigned*)wl + (idx0>>1)) = v;
    }
  }
  __syncthreads();

  const int bl = tid>>5, dl = tid&31;
  const int d = dg*32+dl, bglob = bg*16+bl;
  const float br = bhh[d], bz = bhh[512+d], bn = bhh[1024+d];

  #pragma clang loop unroll(disable)
  for (int tt=0; tt<CH; ++tt){
    const int t = c0+tt;
    if (t == 0){
      for (int j=0;j<4;++j){
        int i4 = tid + j*512;
        *(float4*)&sh[i4*4] = (float4){1.f,1.f,1.f,1.f};
      }
    } else {
      const float* hp = hz + (size_t)((t-1)&1)*NB*HID + (size_t)bg*16*HID;
      for (int j=0;j<4;++j){
        int i4 = tid + j*512;
        *(float4*)&sh[i4*4] = *(const float4*)&hp[i4*4];
      }
    }
    __syncthreads();
    float ar = br, az = bz, an = bn;
    const float* hb = sh + bl*512;
    for (int k=0;k<512;k+=4){
      float4 h4 = *(const float4*)(hb+k);
      int base = (k>>2)*128 + dl*4;
      uint2 wr = *(const uint2*)(wl + base);
      uint2 wz = *(const uint2*)(wl + 16384 + base);
      uint2 wn = *(const uint2*)(wl + 32768 + base);
      ar += h4.x*bf2f(wr.x&0xffffu) + h4.y*bf2f(wr.x>>16) + h4.z*bf2f(wr.y&0xffffu) + h4.w*bf2f(wr.y>>16);
      az += h4.x*bf2f(wz.x&0xffffu) + h4.y*bf2f(wz.x>>16) + h4.z*bf2f(wz.y&0xffffu) + h4.w*bf2f(wz.y>>16);
      an += h4.x*bf2f(wn.x&0xffffu) + h4.y*bf2f(wn.x>>16) + h4.z*bf2f(wn.y&0xffffu) + h4.w*bf2f(wn.y>>16);
    }
    const float* gi = GI + ((size_t)tt*NB + bglob)*G3;
    float r  = fsig(gi[d] + ar);
    float zz = fsig(gi[512+d] + az);
    float n  = ftanh(gi[1024+d] + r*an);
    float hp = hb[d];
    float hv = (1.0f-zz)*n + zz*hp;
    (hz + (size_t)(t&1)*NB*HID)[(size_t)bglob*HID + d] = hv;
    ob[((size_t)t*NB + bglob)*HID + d] = f2bf(hv);
    __syncthreads();
    gbar(cnt, (unsigned long long)(tt+1)*NWG);
  }
}

// ---- Phase D: persistent attention-match scan, Whs LDS-resident -------------
// 256 WGs = bg(16 of 8 b) x dg(16 of 32 d); 512 thr; dyn LDS 153856 B
__global__ __launch_bounds__(512, 2)
void scanD(const bfraw* __restrict__ Whs, const bfraw* __restrict__ o_p,
           const bfraw* __restrict__ o_h,
           const bfraw* __restrict__ WtT, const bfraw* __restrict__ WmT,
           const float* __restrict__ w_e,
           const bfraw* __restrict__ Wcat, const float* __restrict__ bc,
           float* __restrict__ hmbuf, bfraw* __restrict__ hm_bf,
           float* __restrict__ apart, float* __restrict__ Lpart,
           const float* __restrict__ outW, const float* __restrict__ outb,
           float* __restrict__ out, unsigned long long* __restrict__ cnt)
{
  extern __shared__ char smem[];
  bfraw* whs_l = (bfraw*)smem;                          // 256*264 bfraw = 135168 B
  char*  stg   = smem + 135168;                         // 16384 B
  float* c_l   = (float*)(smem + 135168 + 16384);       // 256 f
  float* l_s   = c_l + 256;                             // 256 f
  float* red   = l_s + 256;                             // 16 f
  float* we_s  = red + 16;                              // 32 f

  const int wg = blockIdx.x;
  const int tid = threadIdx.x;
  const int bg = wg>>4, dg = wg&15;

  // ---- preload Whs slice [256 tq][8 b][32 d] -> LDS (stride 264 bfraw) ----
  for (int q=0; q<16; ++q){
    int quad = tid + q*512;                  // 8192
    int tq = quad>>5, b = (quad>>2)&7, dq = quad&3;
    const bfraw* src = Whs + ((size_t)tq*NB + bg*8+b)*HID + dg*32 + dq*8;
    *(uint4*)&whs_l[tq*264 + b*32 + dq*8] = *(const uint4*)src;
  }
  if (tid < 32) we_s[tid] = w_e[dg*32 + tid];
  __syncthreads();

  unsigned long long base = 0;
  #pragma clang loop unroll(disable)
  for (int t=0; t<TSEQ; ++t){
    // ================= P1: c-compute (local) + logits partials =============
    {
      const int b = tid>>6, r = tid&63, e = r>>1, kh = r&1;
      const int gb = bg*8+b, ge = dg*32+e;
      const bfraw* xr = o_h + ((size_t)t*NB + gb)*HID + kh*256;
      const bfraw* wt = WtT + (size_t)ge*HID + kh*256;
      const bfraw* wm = WmT + (size_t)ge*HID + kh*256;
      const float* hr = hmbuf + (size_t)gb*HID + kh*256;
      float acc = 0.f;
      for (int k=0;k<256;k+=4){
        uint2 xu = *(const uint2*)(xr+k);
        uint2 wu = *(const uint2*)(wt+k);
        uint2 mu = *(const uint2*)(wm+k);
        float4 h4 = *(const float4*)(hr+k);
        acc += bf2f(xu.x&0xffffu)*bf2f(wu.x&0xffffu) + bf2f(xu.x>>16)*bf2f(wu.x>>16)
             + bf2f(xu.y&0xffffu)*bf2f(wu.y&0xffffu) + bf2f(xu.y>>16)*bf2f(wu.y>>16);
        acc += h4.x*bf2f(mu.x&0xffffu) + h4.y*bf2f(mu.x>>16)
             + h4.z*bf2f(mu.y&0xffffu) + h4.w*bf2f(mu.y>>16);
      }
      acc += __shfl_xor(acc, 1);
      if (kh==0) c_l[b*32+e] = acc;
    }
    __syncthreads();
    {
      const int wv = tid>>6, lane = tid&63, pair = lane>>2, dq = lane&3;
      const float* cb = c_l + wv*32;
      float* stf = (float*)stg;              // [8][256]
      #pragma unroll 2
      for (int it=0; it<16; ++it){
        int tq = it*16 + pair;
        uint4 u = *(const uint4*)&whs_l[tq*264 + wv*32 + dq*8];
        float s = 0.f;
        #pragma unroll
        for (int j=0;j<4;++j){
          unsigned uu = ((const unsigned*)&u)[j];
          int d0 = dq*8 + j*2;
          s += ftanh(bf2f(uu&0xffffu) + cb[d0])   * we_s[d0];
          s += ftanh(bf2f(uu>>16)     + cb[d0+1]) * we_s[d0+1];
        }
        s += __shfl_xor(s,1); s += __shfl_xor(s,2);
        if (dq==0) stf[wv*256 + tq] = s;
      }
      __syncthreads();
      // write Lpart: 2048 floats
      {
        float4 lv = *(float4*)&((float*)stg)[(tid>>6)*256 + (tid&63)*4];
        *(float4*)&Lpart[ (((size_t)(bg*8+(tid>>6)))*16 + dg)*256 + (tid&63)*4 ] = lv;
      }
    }
    gbar(cnt, base + NWG);

    // ================= P2: reduce -> softmax -> a_t partial ================
    {
      const int b2 = wg>>1, th = wg&1, lane = tid&63;
      float* lp = (float*)stg;               // [16][256]
      #pragma unroll
      for (int i=0;i<2;++i){
        int v4 = tid + i*512;
        *(float4*)&lp[v4*4] = *(const float4*)&Lpart[(size_t)b2*4096 + v4*4];
      }
      __syncthreads();
      float v = -1e30f, e = 0.f;
      if (tid < TSEQ){
        float s = 0.f;
        #pragma unroll
        for (int g=0; g<16; ++g) s += lp[g*256 + tid];
        v = s;
        float m = v;
        #pragma unroll
        for (int off=32; off; off>>=1) m = fmaxf(m, __shfl_xor(m, off));
        if (lane==0) red[tid>>6] = m;
      }
      __syncthreads();
      float mx = fmaxf(fmaxf(red[0],red[1]), fmaxf(red[2],red[3]));
      if (tid < TSEQ){
        e = __expf(v - mx);
        float s = e;
        #pragma unroll
        for (int off=32; off; off>>=1) s += __shfl_xor(s, off);
        if (lane==0) red[8+(tid>>6)] = s;
      }
      __syncthreads();
      float S = red[8]+red[9]+red[10]+red[11];
      if (tid < TSEQ) l_s[tid] = e * __builtin_amdgcn_rcpf(S);
      __syncthreads();
      // a_t partial over tq-half
      const int dgrp = tid&63, tqs = tid>>6;
      const int d8 = dgrp*8;
      float a0=0,a1=0,a2=0,a3=0,a4=0,a5=0,a6=0,a7=0;
      #pragma unroll 4
      for (int i=0;i<16;++i){
        int tq = th*128 + tqs*16 + i;
        float al = l_s[tq];
        uint4 u = *(const uint4*)(o_p + ((size_t)tq*NB + b2)*HID + d8);
        a0 += al*bf2f(u.x&0xffffu); a1 += al*bf2f(u.x>>16);
        a2 += al*bf2f(u.y&0xffffu); a3 += al*bf2f(u.y>>16);
        a4 += al*bf2f(u.z&0xffffu); a5 += al*bf2f(u.z>>16);
        a6 += al*bf2f(u.w&0xffffu); a7 += al*bf2f(u.w>>16);
      }
      float* pt = (float*)stg;               // [8][512] (reuse)
      *(float4*)&pt[tqs*512 + d8]     = (float4){a0,a1,a2,a3};
      *(float4*)&pt[tqs*512 + d8 + 4] = (float4){a4,a5,a6,a7};
      __syncthreads();
      {
        float s = 0.f;
        #pragma unroll
        for (int ss=0; ss<8; ++ss) s += pt[ss*512 + tid];
        apart[(size_t)th*65536 + (size_t)b2*512 + tid] = s;
      }
    }
    gbar(cnt, base + 2*NWG);

    // ================= P3: gate GEMM + state update (WGs 0..31) ============
    if (wg < 32){
      bfraw* As = (bfraw*)stg;               // 128*40
      bfraw* Bs = As + 5120;                 // 64*40
      const int w = tid>>6, lane = tid&63, fr = lane&15, fg = lane>>4;
      const int mw = w>>1, nw = w&1;
      const bfraw* hmr = hm_bf + (size_t)(((t+1)&1))*65536;   // prev slot
      bfraw*       hmw = hm_bf + (size_t)(t&1)*65536;
      f32x4 acc00={0,0,0,0}, acc01={0,0,0,0}, acc10={0,0,0,0}, acc11={0,0,0,0};
      const int m = tid>>2, kq = (tid&3)*8;
      const int n = tid>>3, k4 = (tid&7)*4;
      #pragma clang loop unroll(disable)
      for (int kt=0; kt<48; ++kt){
        int k0 = kt*32, seg = k0>>9, ko = k0&511;
        // stage A
        if (seg==0){
          float4 p0 = *(const float4*)&apart[(size_t)m*512 + ko + kq];
          float4 p1 = *(const float4*)&apart[(size_t)m*512 + ko + kq + 4];
          float4 q0 = *(const float4*)&apart[65536 + (size_t)m*512 + ko + kq];
          float4 q1 = *(const float4*)&apart[65536 + (size_t)m*512 + ko + kq + 4];
          uint4 pk;
          pk.x = (unsigned)f2bf(p0.x+q0.x) | ((unsigned)f2bf(p0.y+q0.y)<<16);
          pk.y = (unsigned)f2bf(p0.z+q0.z) | ((unsigned)f2bf(p0.w+q0.w)<<16);
          pk.z = (unsigned)f2bf(p1.x+q1.x) | ((unsigned)f2bf(p1.y+q1.y)<<16);
          pk.w = (unsigned)f2bf(p1.z+q1.z) | ((unsigned)f2bf(p1.w+q1.w)<<16);
          *(uint4*)&As[m*40 + kq] = pk;
        } else if (seg==1){
          *(uint4*)&As[m*40 + kq] = *(const uint4*)(o_h + ((size_t)t*NB + m)*HID + ko + kq);
        } else {
          *(uint4*)&As[m*40 + kq] = *(const uint4*)(hmr + (size_t)m*512 + ko + kq);
        }
        // stage B
        *(uint2*)&Bs[n*40 + k4] = *(const uint2*)(Wcat + (size_t)(wg*64+n)*1536 + k0 + k4);
        __syncthreads();
        short8 af0 = *(const short8*)&As[(mw*32 + fr)*40 + fg*8];
        short8 af1 = *(const short8*)&As[(mw*32 + 16 + fr)*40 + fg*8];
        short8 bf0 = *(const short8*)&Bs[(nw*32 + fr)*40 + fg*8];
        short8 bf1 = *(const short8*)&Bs[(nw*32 + 16 + fr)*40 + fg*8];
        acc00 = __builtin_amdgcn_mfma_f32_16x16x32_bf16(af0, bf0, acc00, 0,0,0);
        acc01 = __builtin_amdgcn_mfma_f32_16x16x32_bf16(af0, bf1, acc01, 0,0,0);
        acc10 = __builtin_amdgcn_mfma_f32_16x16x32_bf16(af1, bf0, acc10, 0,0,0);
        acc11 = __builtin_amdgcn_mfma_f32_16x16x32_bf16(af1, bf1, acc11, 0,0,0);
        __syncthreads();
      }
      // epilogue: gates gather via shfl, update h
      const int g = fr&3;
      #pragma unroll
      for (int i2=0;i2<2;++i2){
        #pragma unroll
        for (int j2=0;j2<2;++j2){
          f32x4 v = (i2==0) ? ((j2==0)?acc00:acc01) : ((j2==0)?acc10:acc11);
          int np = wg*64 + nw*32 + j2*16 + fr;
          int dd = np>>2;
          #pragma unroll
          for (int rr=0; rr<4; ++rr){
            float x0  = v[rr];
            float x1  = __shfl_xor(x0, 1);
            float x2  = __shfl_xor(x0, 2);
            float x3  = __shfl_xor(x1, 2);
            if (g==0){
              int b3 = mw*32 + i2*16 + fg*4 + rr;
              float hp = hmbuf[(size_t)b3*512 + dd];
              float rg = fsig(x0 + bc[dd]);
              float zg = fsig(x1 + bc[512+dd]);
              float gn = ftanh(x2 + bc[1024+dd] + rg*(x3 + bc[1536+dd]));
              float h = (1.f-zg)*gn + zg*hp;
              hmbuf[(size_t)b3*512 + dd] = h;
              hmw[(size_t)b3*512 + dd] = f2bf(h);
            }
          }
        }
      }
    }
    gbar(cnt, base + 3*NWG);
    base += 3*NWG;
  }

  // ---- output head ----
  if (wg == 0 && tid < NB*3){
    int b = tid/3, c = tid%3;
    float acc = outb[c];
    const float* h = hmbuf + (size_t)b*HID;
    const float* w = outW + (size_t)c*HID;
    for (int d2=0; d2<HID; ++d2) acc = fmaf(h[d2], w[d2], acc);
    out[tid] = fmaxf(acc, 0.f);
  }
}

extern "C" void kernel_launch(void* const* d_in, const int* in_sizes, int n_in,
                              void* d_out, int out_size, void* d_ws, size_t ws_size,
                              hipStream_t stream)
{
  const float* Ep    = (const float*)d_in[0];
  const float* Eh    = (const float*)d_in[1];
  const float* p_W   = (const float*)d_in[2];
  const float* p_b   = (const float*)d_in[3];
  const float* h_W   = (const float*)d_in[4];
  const float* h_b   = (const float*)d_in[5];
  const float* pgWih = (const float*)d_in[6];
  const float* pgWhh = (const float*)d_in[7];
  const float* pgbih = (const float*)d_in[8];
  const float* pgbhh = (const float*)d_in[9];
  const float* hgWih = (const float*)d_in[10];
  const float* hgWhh = (const float*)d_in[11];
  const float* hgbih = (const float*)d_in[12];
  const float* hgbhh = (const float*)d_in[13];
  const float* W_s   = (const float*)d_in[14];
  const float* W_t   = (const float*)d_in[15];
  const float* w_e   = (const float*)d_in[16];
  const float* W_m   = (const float*)d_in[17];
  const float* mWih  = (const float*)d_in[18];
  const float* mWhh  = (const float*)d_in[19];
  const float* mbih  = (const float*)d_in[20];
  const float* mbhh  = (const float*)d_in[21];
  const float* outW  = (const float*)d_in[22];
  const float* outb  = (const float*)d_in[23];

  const size_t OB    = (size_t)TSEQ*NB*HID*sizeof(bfraw);    // 33,554,432
  const size_t RB    = OB;                                    // GI chunks / Whs overlay
  const size_t WFB   = (size_t)G3*INDIM*sizeof(bfraw);        // 2,359,296
  const size_t SQB   = (size_t)HID*HID*sizeof(bfraw);         // 524,288
  const size_t WHHB  = (size_t)G3*HID*sizeof(bfraw);          // 1,572,864
  const size_t WCATB = (size_t)2048*1536*sizeof(bfraw);       // 6,291,456
  const size_t needed = 2*OB + RB + 2*WFB + 3*SQB + 2*WHHB + WCATB
                        + 8192 + 2*6144
                        + 4*262144 /*hst*/ + 262144 /*hmbuf*/ + 2*131072 /*hm_bf*/
                        + 512;
  if (ws_size < needed) return;

  char* p = (char*)d_ws;
  bfraw* o_p_bf = (bfraw*)p; p += OB;
  bfraw* o_h_bf = (bfraw*)p; p += OB;
  char*  Rreg   = p;         p += RB;
  bfraw* Wfp_bf = (bfraw*)p; p += WFB;
  bfraw* Wfh_bf = (bfraw*)p; p += WFB;
  bfraw* WsT_bf = (bfraw*)p; p += SQB;
  bfraw* WtT_bf = (bfraw*)p; p += SQB;
  bfraw* WmT_bf = (bfraw*)p; p += SQB;
  bfraw* Whhp_bf= (bfraw*)p; p += WHHB;
  bfraw* Whhh_bf= (bfraw*)p; p += WHHB;
  bfraw* Wcat_bf= (bfraw*)p; p += WCATB;
  float* bc     = (float*)p; p += 8192;
  float* bfp    = (float*)p; p += 6144;
  float* bfh    = (float*)p; p += 6144;
  float* hst    = (float*)p; p += 4*262144;
  float* hmbuf  = (float*)p; p += 262144;
  bfraw* hm_bf  = (bfraw*)p; p += 2*131072;
  unsigned long long* cnt = (unsigned long long*)p; p += 512;

  // overlays
  bfraw* pWT_bf = (bfraw*)Rreg;                          // phase A only
  bfraw* hWT_bf = (bfraw*)(Rreg + (size_t)INDIM*HID*sizeof(bfraw));
  float* GIp_c  = (float*)Rreg;                          // phase B chunks
  float* GIh_c  = (float*)(Rreg + (size_t)CH*NB*G3*sizeof(float));
  bfraw* Whs_bf = (bfraw*)Rreg;                          // phase C/D
  float* Lpart  = (float*)Wfp_bf;                        // scanD scratch (Wf dead)
  float* apart  = Lpart + (size_t)128*16*256;            // +2MB

  // allow >64KB dynamic LDS
  (void)hipFuncSetAttribute((const void*)scanB, hipFuncAttributeMaxDynamicSharedMemorySize, 131072);
  (void)hipFuncSetAttribute((const void*)scanD, hipFuncAttributeMaxDynamicSharedMemorySize, 153856);

  dim3 b256(256), b512(512);

  init_k<<<dim3(1), dim3(64), 0, stream>>>(cnt);
  hminit_k<<<dim3(256), b256, 0, stream>>>(hmbuf, hm_bf);

  // ---- Phase A: weight prep ----
  tconv_k<<<dim3(INDIM/32, HID/32), b256, 0, stream>>>(p_W, pWT_bf, HID, INDIM);
  tconv_k<<<dim3(INDIM/32, HID/32), b256, 0, stream>>>(h_W, hWT_bf, HID, INDIM);
  tconv_k<<<dim3(HID/32, HID/32),  b256, 0, stream>>>(W_s, WsT_bf, HID, HID);
  tconv_k<<<dim3(HID/32, HID/32),  b256, 0, stream>>>(W_t, WtT_bf, HID, HID);
  tconv_k<<<dim3(HID/32, HID/32),  b256, 0, stream>>>(W_m, WmT_bf, HID, HID);
  cvt_k<<<dim3((G3*HID)/1024), b256, 0, stream>>>(pgWhh, Whhp_bf, G3*HID);
  cvt_k<<<dim3((G3*HID)/1024), b256, 0, stream>>>(hgWhh, Whhh_bf, G3*HID);
  wcat_k<<<dim3(3072), b256, 0, stream>>>(mWih, mWhh, Wcat_bf);
  bpack_k<<<dim3(2), b256, 0, stream>>>(mbih, mbhh, bc);
  fuse_bias_k<<<dim3(G3/256), b256, 0, stream>>>(pgWih, pgbih, p_b, bfp);
  fuse_bias_k<<<dim3(G3/256), b256, 0, stream>>>(hgWih, hgbih, h_b, bfh);
  mgemm<float, bfraw, false><<<dim3(INDIM/128, G3/128, 2), b256, 0, stream>>>(
    pgWih, hgWih, pWT_bf, hWT_bf, nullptr, nullptr, Wfp_bf, Wfh_bf,
    HID, HID, HID, INDIM);

  // ---- Phase B: chunked GI GEMM + persistent scan ----
  for (int c = 0; c < TSEQ/CH; ++c){
    mgemm<float, float, true><<<dim3(G3/128, (CH*NB)/128, 2), b256, 0, stream>>>(
      Ep + (size_t)c*CH*NB*INDIM, Eh + (size_t)c*CH*NB*INDIM,
      Wfp_bf, Wfh_bf, bfp, bfh, GIp_c, GIh_c,
      INDIM, INDIM, INDIM, G3);
    scanB<<<dim3(NWG), b512, 131072, stream>>>(
      GIp_c, GIh_c, Whhp_bf, Whhh_bf, pgbhh, hgbhh,
      hst, o_p_bf, o_h_bf, c*CH, cnt + c);
  }

  // ---- Phase C: Whs = o_p @ W_s ----
  mgemm<bfraw, bfraw, false><<<dim3(HID/128, (TSEQ*NB)/128, 1), b256, 0, stream>>>(
    o_p_bf, o_p_bf, WsT_bf, WsT_bf, nullptr, nullptr, Whs_bf, Whs_bf,
    HID, HID, HID, HID);

  // ---- Phase D: persistent attention-match scan + fused head ----
  scanD<<<dim3(NWG), b512, 153856, stream>>>(
    Whs_bf, o_p_bf, o_h_bf, WtT_bf, WmT_bf, w_e, Wcat_bf, bc,
    hmbuf, hm_bf, apart, Lpart, outW, outb, (float*)d_out, cnt + 16);
}